// Round 6
// baseline (297.615 us; speedup 1.0000x reference)
//
#include <hip/hip_runtime.h>
#include <stdint.h>

#define BATCH 2
#define SEQ 2048
#define DMODEL 1024
#define NHEAD 16
#define HDIM 64
#define CVT_BLOCKS 15360

typedef __attribute__((ext_vector_type(8))) short bf16x8;
typedef __attribute__((ext_vector_type(4))) float f32x4;

__device__ __forceinline__ unsigned short f2bf(float f) {
  unsigned int u = __float_as_uint(f);
  u += 0x7fffu + ((u >> 16) & 1u);
  return (unsigned short)(u >> 16);
}
// pack 2 f32 -> 2 bf16 (round-to-nearest-ties-away): 2 adds + 1 v_perm
__device__ __forceinline__ unsigned int pk2bf(float a, float b) {
  return __builtin_amdgcn_perm(__float_as_uint(b) + 0x8000u,
                               __float_as_uint(a) + 0x8000u, 0x07060302u);
}
__device__ __forceinline__ void async_copy16(const void* g, void* l) {
  __builtin_amdgcn_global_load_lds(
      (const __attribute__((address_space(1))) void*)g,
      (__attribute__((address_space(3))) void*)l, 16, 0, 0);
}

// ---- fp32 -> bf16 for q,k,v,Wq,Wk,Wv; block CVT_BLOCKS computes mask lens ----
__global__ __launch_bounds__(256) void cvt_all(
    const float* __restrict__ q, const float* __restrict__ k,
    const float* __restrict__ v, const float* __restrict__ Wq,
    const float* __restrict__ Wk, const float* __restrict__ Wv,
    unsigned short* __restrict__ dst,
    const unsigned char* __restrict__ kp, const unsigned char* __restrict__ qp,
    int* __restrict__ lens) {
  if (blockIdx.x == CVT_BLOCKS) {  // klen->lens[0..1], qlen->lens[2..3]
    const int t = threadIdx.x, wave = t >> 6, lane = t & 63;
    const unsigned char* base = (wave < 2) ? kp : qp;
    const int b = wave & 1;
    const bool bytefmt = (base[1] != 0);  // element 1 always valid (len>=S/2)
    int cnt = 0;
    if (bytefmt) {
      const uint4* p = (const uint4*)(base + (size_t)b * SEQ);
#pragma unroll
      for (int g = 0; g < 2; g++) {
        const uint4 x = p[g * 64 + lane];
        const unsigned int w[4] = {x.x, x.y, x.z, x.w};
#pragma unroll
        for (int i = 0; i < 4; i++) {
          const unsigned int ww = w[i];
          cnt += ((ww & 0xffu) != 0) + ((ww & 0xff00u) != 0) +
                 ((ww & 0xff0000u) != 0) + ((ww & 0xff000000u) != 0);
        }
      }
    } else {
      const uint4* p = (const uint4*)(base + (size_t)b * SEQ * 4);
#pragma unroll
      for (int g = 0; g < 8; g++) {
        const uint4 x = p[g * 64 + lane];
        cnt += (x.x != 0) + (x.y != 0) + (x.z != 0) + (x.w != 0);
      }
    }
#pragma unroll
    for (int off = 32; off >= 1; off >>= 1) cnt += __shfl_xor(cnt, off, 64);
    if (lane == 0) lens[wave] = cnt;
    return;
  }
  const int g = blockIdx.x * 256 + threadIdx.x;
  const float* src;
  size_t off, dbase;
  if (g < 3 * (1 << 20)) {
    const int ti = g >> 20;
    src = (ti == 0) ? q : (ti == 1) ? k : v;
    off = (size_t)(g & ((1 << 20) - 1));
    dbase = (size_t)ti << 22;
  } else {
    const int gw = g - 3 * (1 << 20);
    const int ti = gw >> 18;
    src = (ti == 0) ? Wq : (ti == 1) ? Wk : Wv;
    off = (size_t)(gw & ((1 << 18) - 1));
    dbase = (3ull << 22) + ((size_t)ti << 20);
  }
  const float4 x = ((const float4*)src)[off];
  ushort4 o;
  o.x = f2bf(x.x); o.y = f2bf(x.y); o.z = f2bf(x.z); o.w = f2bf(x.w);
  *(ushort4*)(dst + dbase + off * 4) = o;
}

// ---- fused QKV projection. Q pre-scaled by (1/sqrt(64))*log2(e).
// z==2 (V): swapped-operand MFMA -> transposed accumulator -> writes V^T[b,h,d,s].
__global__ __launch_bounds__(256) void qkv_proj(
    const unsigned short* __restrict__ xq, const unsigned short* __restrict__ xk,
    const unsigned short* __restrict__ xv,
    const unsigned short* __restrict__ Wq, const float* __restrict__ bq,
    const unsigned short* __restrict__ Wk, const float* __restrict__ bk,
    const unsigned short* __restrict__ Wv, const float* __restrict__ bv,
    unsigned short* __restrict__ Qo, unsigned short* __restrict__ Ko,
    unsigned short* __restrict__ Vo) {
  const int z = blockIdx.z;
  const unsigned short* x = (z == 0) ? xq : (z == 1) ? xk : xv;
  const unsigned short* W = (z == 0) ? Wq : (z == 1) ? Wk : Wv;
  const float* bias = (z == 0) ? bq : (z == 1) ? bk : bv;
  unsigned short* dst = (z == 0) ? Qo : (z == 1) ? Ko : Vo;
  const float osc = (z == 0) ? 0.18033688011112042f : 1.0f;

  __shared__ unsigned short As[128 * 32];
  __shared__ unsigned short Bs[128 * 32];

  const int t = threadIdx.x;
  const int wave = t >> 6, lane = t & 63, quad = lane >> 4, l16 = lane & 15;
  const int wm = wave >> 1, wn = wave & 1;
  const int m0 = blockIdx.y * 128, n0 = blockIdx.x * 128;

  const f32x4 fz = {0.f, 0.f, 0.f, 0.f};
  f32x4 acc[4][4];
#pragma unroll
  for (int i = 0; i < 4; i++)
#pragma unroll
    for (int j = 0; j < 4; j++) acc[i][j] = fz;

  for (int k0 = 0; k0 < DMODEL; k0 += 32) {
    __syncthreads();
#pragma unroll
    for (int c = 0; c < 2; c++) {
      const int g = c * 256 + t;
      const int row = g >> 2, cc = g & 3;
      async_copy16(x + (size_t)(m0 + row) * DMODEL + k0 + cc * 8,
                   (char*)As + (c * 256 + (t & 192)) * 16);
      async_copy16(W + (size_t)(n0 + row) * DMODEL + k0 + cc * 8,
                   (char*)Bs + (c * 256 + (t & 192)) * 16);
    }
    __syncthreads();
    bf16x8 af[4], bfr[4];
#pragma unroll
    for (int i = 0; i < 4; i++) {
      af[i] = *(const bf16x8*)(As + (wm * 64 + i * 16 + l16) * 32 + quad * 8);
      bfr[i] = *(const bf16x8*)(Bs + (wn * 64 + i * 16 + l16) * 32 + quad * 8);
    }
    if (z == 2) {
#pragma unroll
      for (int i = 0; i < 4; i++)
#pragma unroll
        for (int j = 0; j < 4; j++)
          acc[i][j] = __builtin_amdgcn_mfma_f32_16x16x32_bf16(bfr[j], af[i], acc[i][j], 0, 0, 0);
    } else {
#pragma unroll
      for (int i = 0; i < 4; i++)
#pragma unroll
        for (int j = 0; j < 4; j++)
          acc[i][j] = __builtin_amdgcn_mfma_f32_16x16x32_bf16(af[i], bfr[j], acc[i][j], 0, 0, 0);
    }
  }

  if (z == 2) {
    // acc[i][j]: rows (quad*4+r) = out-dim within j-frag, cols (l16) = seq within i-frag
#pragma unroll
    for (int j = 0; j < 4; j++) {
#pragma unroll
      for (int i = 0; i < 4; i++) {
#pragma unroll
        for (int r = 0; r < 4; r++) {
          const int n = n0 + wn * 64 + j * 16 + quad * 4 + r;  // output dim
          const int m = m0 + wm * 64 + i * 16 + l16;           // batch*seq
          const int bb = m >> 11, s = m & (SEQ - 1);
          const int hh = n >> 6, hd = n & 63;
          dst[(((size_t)(bb * NHEAD + hh) * HDIM + hd) << 11) + s] =
              f2bf(acc[i][j][r] + bias[n]);
        }
      }
    }
  } else {
#pragma unroll
    for (int j = 0; j < 4; j++) {
      const int n = n0 + wn * 64 + j * 16 + l16;
      const float bf_ = bias[n];
      const int hh = n >> 6, hd = n & 63;
#pragma unroll
      for (int i = 0; i < 4; i++) {
#pragma unroll
        for (int r = 0; r < 4; r++) {
          const int m = m0 + wm * 64 + i * 16 + quad * 4 + r;
          const int bb = m >> 11, s = m & (SEQ - 1);
          dst[(((size_t)(bb * NHEAD + hh) * SEQ + s) << 6) + hd] = f2bf((acc[i][j][r] + bf_) * osc);
        }
      }
    }
  }
}

// ===== attention v5: paired causal tiles, 128-key chunks, async K & V^T =====
// Block pi: lo=pi, hi=31-pi (uniform ~33 MFMA-tiles). 512 blocks, 48KB LDS ->
// 3 blocks/CU slots. Swapped QK mfma(kf,qf): lane owns q=l16. XOR-swizzled LDS.

template <bool MASKED>
__device__ __forceinline__ void softmax_update(
    const f32x4 s[8], int key0, int qrow, int klen, int quad, int l16,
    float& mst, float& lsum, f32x4 o[4], unsigned short* Pdst) {
  float pm[8][4];
  float rm = -__builtin_inff();
  if (MASKED) {
    const int kmax = ((qrow < klen - 1) ? qrow : klen - 1) - key0 - quad * 4;
#pragma unroll
    for (int nf = 0; nf < 8; nf++)
#pragma unroll
      for (int r = 0; r < 4; r++) {
        pm[nf][r] = (nf * 16 + r <= kmax) ? s[nf][r] : -__builtin_inff();
        rm = fmaxf(rm, pm[nf][r]);
      }
  } else {
#pragma unroll
    for (int nf = 0; nf < 8; nf++)
#pragma unroll
      for (int r = 0; r < 4; r++) {
        pm[nf][r] = s[nf][r];
        rm = fmaxf(rm, pm[nf][r]);
      }
  }
  rm = fmaxf(rm, __shfl_xor(rm, 16, 64));
  rm = fmaxf(rm, __shfl_xor(rm, 32, 64));
  if (__ballot(rm > mst) != 0ull) {
    const float mnew = fmaxf(mst, rm);
    const float alpha = exp2f(fmaxf(mst, -1e30f) - fmaxf(mnew, -1e30f));
    mst = mnew;
    lsum *= alpha;
    float ab[4];
#pragma unroll
    for (int r = 0; r < 4; r++) ab[r] = __shfl(alpha, quad * 4 + r, 64);
#pragma unroll
    for (int db = 0; db < 4; db++)
#pragma unroll
      for (int r = 0; r < 4; r++) o[db][r] *= ab[r];
  }
  const float mref = fmaxf(mst, -1e30f);
  float rs = 0.f;
#pragma unroll
  for (int nf = 0; nf < 8; nf++)
#pragma unroll
    for (int r = 0; r < 4; r++) {
      const float p = exp2f(pm[nf][r] - mref);
      pm[nf][r] = p;
      rs += p;
    }
  rs += __shfl_xor(rs, 16, 64);
  rs += __shfl_xor(rs, 32, 64);
  lsum += rs;
#pragma unroll
  for (int nf = 0; nf < 8; nf++) {
    uint2 w;
    w.x = pk2bf(pm[nf][0], pm[nf][1]);
    w.y = pk2bf(pm[nf][2], pm[nf][3]);
    const int grp = (nf * 2 + (quad >> 1)) ^ l16;
    *(uint2*)(Pdst + l16 * 128 + grp * 8 + (quad & 1) * 4) = w;
  }
}

__device__ __forceinline__ void pv_accum(f32x4 o[4], const unsigned short* Pw,
                                         const unsigned short* vt, int quad, int l16) {
  bf16x8 pf[4];
#pragma unroll
  for (int ks = 0; ks < 4; ks++)
    pf[ks] = *(const bf16x8*)(Pw + l16 * 128 + ((ks * 4 + quad) ^ l16) * 8);
#pragma unroll
  for (int db = 0; db < 4; db++) {
    const int d = db * 16 + l16;
#pragma unroll
    for (int ks = 0; ks < 4; ks++) {
      const bf16x8 v = *(const bf16x8*)(vt + d * 128 + ((ks * 4 + quad) ^ l16) * 8);
      o[db] = __builtin_amdgcn_mfma_f32_16x16x32_bf16(pf[ks], v, o[db], 0, 0, 0);
    }
  }
}

__global__ __launch_bounds__(256, 3) void attn_kernel(
    const unsigned short* __restrict__ Qb, const unsigned short* __restrict__ Kb,
    const unsigned short* __restrict__ VTb, const float* __restrict__ qin,
    const int* __restrict__ lens, float* __restrict__ out) {
  const int pi = blockIdx.x, h = blockIdx.y, b = blockIdx.z;
  const int lo = pi, hi = 31 - pi;
  const int bh = b * NHEAD + h;
  const int t = threadIdx.x, wave = t >> 6, lane = t & 63, quad = lane >> 4, l16 = lane & 15;
  const int klen = lens[b], qlen = lens[2 + b];
  const bool doHI = (hi * 64 < qlen);

  __shared__ unsigned short Ks[128 * 64];     // [key][d], swizzle row&7
  __shared__ unsigned short VT[64 * 128];     // [d][key], swizzle d&15
  __shared__ unsigned short Ps[4][16 * 128];  // per-wave P, reused hi->lo

  const unsigned short* Qp = Qb + (size_t)bh * SEQ * HDIM;
  const unsigned short* Kp = Kb + (size_t)bh * SEQ * HDIM;
  const unsigned short* Vt = VTb + (size_t)bh * HDIM * SEQ;

  const int qrLO = lo * 64 + wave * 16 + l16;
  const int qrHI = hi * 64 + wave * 16 + l16;
  const bf16x8 qlo0 = *(const bf16x8*)(Qp + (size_t)qrLO * HDIM + quad * 8);
  const bf16x8 qlo1 = *(const bf16x8*)(Qp + (size_t)qrLO * HDIM + 32 + quad * 8);
  const bf16x8 qhi0 = *(const bf16x8*)(Qp + (size_t)qrHI * HDIM + quad * 8);
  const bf16x8 qhi1 = *(const bf16x8*)(Qp + (size_t)qrHI * HDIM + 32 + quad * 8);

  const f32x4 fz = {0.f, 0.f, 0.f, 0.f};
  f32x4 oLO[4], oHI[4];
#pragma unroll
  for (int i = 0; i < 4; i++) { oLO[i] = fz; oHI[i] = fz; }
  float mLO = -__builtin_inff(), lLO = 0.f;
  float mHI = -__builtin_inff(), lHI = 0.f;

  const int kendLO = ((lo * 64 + 64) < klen) ? (lo * 64 + 64) : klen;
  const int ktotLO = (kendLO + 127) >> 7;
  int ktotHI = 0;
  if (doHI) {
    const int kendHI = ((hi * 64 + 64) < klen) ? (hi * 64 + 64) : klen;
    ktotHI = (kendHI + 127) >> 7;
  }
  const int ktot = (ktotHI > ktotLO) ? ktotHI : ktotLO;

  for (int kt = 0; kt < ktot; kt++) {
    const int key0 = kt << 7;
    __syncthreads();  // all waves done with previous chunk's LDS
    // stage K: 128 rows x 64d (8 groups of 16B, swizzle row&7)
#pragma unroll
    for (int c = 0; c < 4; c++) {
      const int slot = c * 256 + t;
      const int row = slot >> 3, pg = slot & 7;
      async_copy16(Kp + (size_t)(key0 + row) * HDIM + (pg ^ (row & 7)) * 8,
                   (char*)Ks + (c * 256 + (t & 192)) * 16);
    }
    // stage V^T: 64 rows x 128keys (16 groups of 16B, swizzle row&15)
#pragma unroll
    for (int c = 0; c < 4; c++) {
      const int slot = c * 256 + t;
      const int row = slot >> 4, pg = slot & 15;
      async_copy16(Vt + (size_t)row * SEQ + key0 + (pg ^ (row & 15)) * 8,
                   (char*)VT + (c * 256 + (t & 192)) * 16);
    }
    __syncthreads();  // async copies drained

    const bool cLO = (kt < ktotLO), cHI = (kt < ktotHI);
    f32x4 sLO[8], sHI[8];
#pragma unroll
    for (int nf = 0; nf < 8; nf++) {
      const int row = nf * 16 + l16;
      const int sw = row & 7;
      const bf16x8 kf0 = *(const bf16x8*)(Ks + row * 64 + (quad ^ sw) * 8);
      const bf16x8 kf1 = *(const bf16x8*)(Ks + row * 64 + ((quad + 4) ^ sw) * 8);
      if (cHI) {
        f32x4 a = fz;
        a = __builtin_amdgcn_mfma_f32_16x16x32_bf16(kf0, qhi0, a, 0, 0, 0);
        a = __builtin_amdgcn_mfma_f32_16x16x32_bf16(kf1, qhi1, a, 0, 0, 0);
        sHI[nf] = a;
      }
      if (cLO) {
        f32x4 a = fz;
        a = __builtin_amdgcn_mfma_f32_16x16x32_bf16(kf0, qlo0, a, 0, 0, 0);
        a = __builtin_amdgcn_mfma_f32_16x16x32_bf16(kf1, qlo1, a, 0, 0, 0);
        sLO[nf] = a;
      }
    }
    if (cHI) {
      if ((key0 + 127 <= hi * 64) && (key0 + 127 < klen))
        softmax_update<false>(sHI, key0, qrHI, klen, quad, l16, mHI, lHI, oHI, Ps[wave]);
      else
        softmax_update<true>(sHI, key0, qrHI, klen, quad, l16, mHI, lHI, oHI, Ps[wave]);
      pv_accum(oHI, Ps[wave], VT, quad, l16);
    }
    if (cLO) {
      if ((key0 + 127 <= lo * 64) && (key0 + 127 < klen))
        softmax_update<false>(sLO, key0, qrLO, klen, quad, l16, mLO, lLO, oLO, Ps[wave]);
      else
        softmax_update<true>(sLO, key0, qrLO, klen, quad, l16, mLO, lLO, oLO, Ps[wave]);
      pv_accum(oLO, Ps[wave], VT, quad, l16);
    }
  }

  const float invLO = (lLO > 0.f) ? 1.f / lLO : 0.f;
  const float invHI = (lHI > 0.f) ? 1.f / lHI : 0.f;
  float ibLO[4], ibHI[4];
#pragma unroll
  for (int r = 0; r < 4; r++) {
    ibLO[r] = __shfl(invLO, quad * 4 + r, 64);
    ibHI[r] = __shfl(invHI, quad * 4 + r, 64);
  }
#pragma unroll
  for (int db = 0; db < 4; db++) {
    const int col = h * HDIM + db * 16 + l16;
#pragma unroll
    for (int r = 0; r < 4; r++) {
      const int iL = lo * 64 + wave * 16 + quad * 4 + r;
      const int iH = hi * 64 + wave * 16 + quad * 4 + r;
      const size_t oL = (size_t)(b * SEQ + iL) * DMODEL + col;
      const size_t oH = (size_t)(b * SEQ + iH) * DMODEL + col;
      out[oL] = ((iL < qlen) ? oLO[db][r] * ibLO[r] : 0.f) + qin[oL];
      out[oH] = ((iH < qlen) ? oHI[db][r] * ibHI[r] : 0.f) + qin[oH];
    }
  }
}

extern "C" void kernel_launch(void* const* d_in, const int* in_sizes, int n_in,
                              void* d_out, int out_size, void* d_ws, size_t ws_size,
                              hipStream_t stream) {
  (void)in_sizes; (void)n_in; (void)out_size; (void)ws_size;
  const float* q = (const float*)d_in[0];
  const float* k = (const float*)d_in[1];
  const float* v = (const float*)d_in[2];
  const float* Wq = (const float*)d_in[3];
  const float* bq = (const float*)d_in[4];
  const float* Wk = (const float*)d_in[5];
  const float* bk = (const float*)d_in[6];
  const float* Wv = (const float*)d_in[7];
  const float* bv = (const float*)d_in[8];
  const unsigned char* kpm = (const unsigned char*)d_in[9];
  const unsigned char* qpm = (const unsigned char*)d_in[10];
  float* out = (float*)d_out;

  const size_t tsz = (size_t)BATCH * SEQ * DMODEL;  // 4 Mi
  const size_t wsz = (size_t)DMODEL * DMODEL;       // 1 Mi

  char* ws = (char*)d_ws;
  int* lens = (int*)ws;
  unsigned short* cvt_base = (unsigned short*)(ws + 256);
  unsigned short* qb16 = cvt_base;
  unsigned short* kb16 = qb16 + tsz;
  unsigned short* vb16 = kb16 + tsz;
  unsigned short* Wqb = vb16 + tsz;
  unsigned short* Wkb = Wqb + wsz;
  unsigned short* Wvb = Wkb + wsz;
  unsigned short* Qw = Wvb + wsz;
  unsigned short* Kw = Qw + tsz;
  unsigned short* Vtw = Kw + tsz;  // V^T [b,h,d,s]

  cvt_all<<<dim3(CVT_BLOCKS + 1), dim3(256), 0, stream>>>(q, k, v, Wq, Wk, Wv,
                                                          cvt_base, kpm, qpm, lens);
  qkv_proj<<<dim3(8, 32, 3), dim3(256), 0, stream>>>(qb16, kb16, vb16, Wqb, bq, Wkb, bk, Wvb, bv, Qw, Kw, Vtw);
  attn_kernel<<<dim3(16, NHEAD, BATCH), dim3(256), 0, stream>>>(Qw, Kw, Vtw, q, lens, out);
}

// Round 7
// 219.613 us; speedup vs baseline: 1.3552x; 1.3552x over previous
//
#include <hip/hip_runtime.h>
#include <stdint.h>

#define BATCH 2
#define SEQ 2048
#define DMODEL 1024
#define NHEAD 16
#define HDIM 64
#define CVT_BLOCKS 15360

typedef __attribute__((ext_vector_type(8))) short bf16x8;
typedef __attribute__((ext_vector_type(4))) float f32x4;

__device__ __forceinline__ unsigned short f2bf(float f) {
  unsigned int u = __float_as_uint(f);
  u += 0x7fffu + ((u >> 16) & 1u);
  return (unsigned short)(u >> 16);
}
// pack 2 f32 -> 2 bf16 (round-to-nearest-ties-away): 2 adds + 1 v_perm
__device__ __forceinline__ unsigned int pk2bf(float a, float b) {
  return __builtin_amdgcn_perm(__float_as_uint(b) + 0x8000u,
                               __float_as_uint(a) + 0x8000u, 0x07060302u);
}
__device__ __forceinline__ void async_copy16(const void* g, void* l) {
  __builtin_amdgcn_global_load_lds(
      (const __attribute__((address_space(1))) void*)g,
      (__attribute__((address_space(3))) void*)l, 16, 0, 0);
}

// ---- fp32 -> bf16 for q,k,v,Wq,Wk,Wv; block CVT_BLOCKS computes mask lens ----
__global__ __launch_bounds__(256) void cvt_all(
    const float* __restrict__ q, const float* __restrict__ k,
    const float* __restrict__ v, const float* __restrict__ Wq,
    const float* __restrict__ Wk, const float* __restrict__ Wv,
    unsigned short* __restrict__ dst,
    const unsigned char* __restrict__ kp, const unsigned char* __restrict__ qp,
    int* __restrict__ lens) {
  if (blockIdx.x == CVT_BLOCKS) {  // klen->lens[0..1], qlen->lens[2..3]
    const int t = threadIdx.x, wave = t >> 6, lane = t & 63;
    const unsigned char* base = (wave < 2) ? kp : qp;
    const int b = wave & 1;
    const bool bytefmt = (base[1] != 0);  // element 1 always valid (len>=S/2)
    int cnt = 0;
    if (bytefmt) {
      const uint4* p = (const uint4*)(base + (size_t)b * SEQ);
#pragma unroll
      for (int g = 0; g < 2; g++) {
        const uint4 x = p[g * 64 + lane];
        const unsigned int w[4] = {x.x, x.y, x.z, x.w};
#pragma unroll
        for (int i = 0; i < 4; i++) {
          const unsigned int ww = w[i];
          cnt += ((ww & 0xffu) != 0) + ((ww & 0xff00u) != 0) +
                 ((ww & 0xff0000u) != 0) + ((ww & 0xff000000u) != 0);
        }
      }
    } else {
      const uint4* p = (const uint4*)(base + (size_t)b * SEQ * 4);
#pragma unroll
      for (int g = 0; g < 8; g++) {
        const uint4 x = p[g * 64 + lane];
        cnt += (x.x != 0) + (x.y != 0) + (x.z != 0) + (x.w != 0);
      }
    }
#pragma unroll
    for (int off = 32; off >= 1; off >>= 1) cnt += __shfl_xor(cnt, off, 64);
    if (lane == 0) lens[wave] = cnt;
    return;
  }
  const int g = blockIdx.x * 256 + threadIdx.x;
  const float* src;
  size_t off, dbase;
  if (g < 3 * (1 << 20)) {
    const int ti = g >> 20;
    src = (ti == 0) ? q : (ti == 1) ? k : v;
    off = (size_t)(g & ((1 << 20) - 1));
    dbase = (size_t)ti << 22;
  } else {
    const int gw = g - 3 * (1 << 20);
    const int ti = gw >> 18;
    src = (ti == 0) ? Wq : (ti == 1) ? Wk : Wv;
    off = (size_t)(gw & ((1 << 18) - 1));
    dbase = (3ull << 22) + ((size_t)ti << 20);
  }
  const float4 x = ((const float4*)src)[off];
  ushort4 o;
  o.x = f2bf(x.x); o.y = f2bf(x.y); o.z = f2bf(x.z); o.w = f2bf(x.w);
  *(ushort4*)(dst + dbase + off * 4) = o;
}

// ---- fused QKV projection. Q pre-scaled by (1/sqrt(64))*log2(e).
// z==2 (V): swapped-operand MFMA -> transposed accumulator -> writes V^T[b,h,d,s].
__global__ __launch_bounds__(256) void qkv_proj(
    const unsigned short* __restrict__ xq, const unsigned short* __restrict__ xk,
    const unsigned short* __restrict__ xv,
    const unsigned short* __restrict__ Wq, const float* __restrict__ bq,
    const unsigned short* __restrict__ Wk, const float* __restrict__ bk,
    const unsigned short* __restrict__ Wv, const float* __restrict__ bv,
    unsigned short* __restrict__ Qo, unsigned short* __restrict__ Ko,
    unsigned short* __restrict__ Vo) {
  const int z = blockIdx.z;
  const unsigned short* x = (z == 0) ? xq : (z == 1) ? xk : xv;
  const unsigned short* W = (z == 0) ? Wq : (z == 1) ? Wk : Wv;
  const float* bias = (z == 0) ? bq : (z == 1) ? bk : bv;
  unsigned short* dst = (z == 0) ? Qo : (z == 1) ? Ko : Vo;
  const float osc = (z == 0) ? 0.18033688011112042f : 1.0f;

  __shared__ unsigned short As[128 * 32];
  __shared__ unsigned short Bs[128 * 32];

  const int t = threadIdx.x;
  const int wave = t >> 6, lane = t & 63, quad = lane >> 4, l16 = lane & 15;
  const int wm = wave >> 1, wn = wave & 1;
  const int m0 = blockIdx.y * 128, n0 = blockIdx.x * 128;

  const f32x4 fz = {0.f, 0.f, 0.f, 0.f};
  f32x4 acc[4][4];
#pragma unroll
  for (int i = 0; i < 4; i++)
#pragma unroll
    for (int j = 0; j < 4; j++) acc[i][j] = fz;

  for (int k0 = 0; k0 < DMODEL; k0 += 32) {
    __syncthreads();
#pragma unroll
    for (int c = 0; c < 2; c++) {
      const int g = c * 256 + t;
      const int row = g >> 2, cc = g & 3;
      async_copy16(x + (size_t)(m0 + row) * DMODEL + k0 + cc * 8,
                   (char*)As + (c * 256 + (t & 192)) * 16);
      async_copy16(W + (size_t)(n0 + row) * DMODEL + k0 + cc * 8,
                   (char*)Bs + (c * 256 + (t & 192)) * 16);
    }
    __syncthreads();
    bf16x8 af[4], bfr[4];
#pragma unroll
    for (int i = 0; i < 4; i++) {
      af[i] = *(const bf16x8*)(As + (wm * 64 + i * 16 + l16) * 32 + quad * 8);
      bfr[i] = *(const bf16x8*)(Bs + (wn * 64 + i * 16 + l16) * 32 + quad * 8);
    }
    if (z == 2) {
#pragma unroll
      for (int i = 0; i < 4; i++)
#pragma unroll
        for (int j = 0; j < 4; j++)
          acc[i][j] = __builtin_amdgcn_mfma_f32_16x16x32_bf16(bfr[j], af[i], acc[i][j], 0, 0, 0);
    } else {
#pragma unroll
      for (int i = 0; i < 4; i++)
#pragma unroll
        for (int j = 0; j < 4; j++)
          acc[i][j] = __builtin_amdgcn_mfma_f32_16x16x32_bf16(af[i], bfr[j], acc[i][j], 0, 0, 0);
    }
  }

  if (z == 2) {
    // acc[i][j]: rows (quad*4+r) = out-dim within j-frag, cols (l16) = seq within i-frag
#pragma unroll
    for (int j = 0; j < 4; j++) {
#pragma unroll
      for (int i = 0; i < 4; i++) {
#pragma unroll
        for (int r = 0; r < 4; r++) {
          const int n = n0 + wn * 64 + j * 16 + quad * 4 + r;  // output dim
          const int m = m0 + wm * 64 + i * 16 + l16;           // batch*seq
          const int bb = m >> 11, s = m & (SEQ - 1);
          const int hh = n >> 6, hd = n & 63;
          dst[(((size_t)(bb * NHEAD + hh) * HDIM + hd) << 11) + s] =
              f2bf(acc[i][j][r] + bias[n]);
        }
      }
    }
  } else {
#pragma unroll
    for (int j = 0; j < 4; j++) {
      const int n = n0 + wn * 64 + j * 16 + l16;
      const float bf_ = bias[n];
      const int hh = n >> 6, hd = n & 63;
#pragma unroll
      for (int i = 0; i < 4; i++) {
#pragma unroll
        for (int r = 0; r < 4; r++) {
          const int m = m0 + wm * 64 + i * 16 + quad * 4 + r;
          const int bb = m >> 11, s = m & (SEQ - 1);
          dst[(((size_t)(bb * NHEAD + hh) * SEQ + s) << 6) + hd] = f2bf((acc[i][j][r] + bf_) * osc);
        }
      }
    }
  }
}

// ===== attention v6: paired causal tiles, SEQUENTIAL per-tile processing =====
// Block pi: lo=pi, hi=31-pi. Per chunk: stage K+V^T once; process HI fully,
// then LO fully (one live s[8] array -> no spills). XOR-swizzled LDS.

template <bool MASKED>
__device__ __forceinline__ void softmax_update(
    const f32x4 s[8], int key0, int qrow, int klen, int quad, int l16,
    float& mst, float& lsum, f32x4 o[4], unsigned short* Pdst) {
  float pm[8][4];
  float rm = -__builtin_inff();
  if (MASKED) {
    const int kmax = ((qrow < klen - 1) ? qrow : klen - 1) - key0 - quad * 4;
#pragma unroll
    for (int nf = 0; nf < 8; nf++)
#pragma unroll
      for (int r = 0; r < 4; r++) {
        pm[nf][r] = (nf * 16 + r <= kmax) ? s[nf][r] : -__builtin_inff();
        rm = fmaxf(rm, pm[nf][r]);
      }
  } else {
#pragma unroll
    for (int nf = 0; nf < 8; nf++)
#pragma unroll
      for (int r = 0; r < 4; r++) {
        pm[nf][r] = s[nf][r];
        rm = fmaxf(rm, pm[nf][r]);
      }
  }
  rm = fmaxf(rm, __shfl_xor(rm, 16, 64));
  rm = fmaxf(rm, __shfl_xor(rm, 32, 64));
  if (__ballot(rm > mst) != 0ull) {
    const float mnew = fmaxf(mst, rm);
    const float alpha = exp2f(fmaxf(mst, -1e30f) - fmaxf(mnew, -1e30f));
    mst = mnew;
    lsum *= alpha;
    float ab[4];
#pragma unroll
    for (int r = 0; r < 4; r++) ab[r] = __shfl(alpha, quad * 4 + r, 64);
#pragma unroll
    for (int db = 0; db < 4; db++)
#pragma unroll
      for (int r = 0; r < 4; r++) o[db][r] *= ab[r];
  }
  const float mref = fmaxf(mst, -1e30f);
  float rs = 0.f;
#pragma unroll
  for (int nf = 0; nf < 8; nf++)
#pragma unroll
    for (int r = 0; r < 4; r++) {
      const float p = exp2f(pm[nf][r] - mref);
      pm[nf][r] = p;
      rs += p;
    }
  rs += __shfl_xor(rs, 16, 64);
  rs += __shfl_xor(rs, 32, 64);
  lsum += rs;
#pragma unroll
  for (int nf = 0; nf < 8; nf++) {
    uint2 w;
    w.x = pk2bf(pm[nf][0], pm[nf][1]);
    w.y = pk2bf(pm[nf][2], pm[nf][3]);
    const int grp = (nf * 2 + (quad >> 1)) ^ l16;
    *(uint2*)(Pdst + l16 * 128 + grp * 8 + (quad & 1) * 4) = w;
  }
}

// full tile pass: QK (from LDS K) -> softmax -> PV (from LDS V^T)
template <bool MASKED>
__device__ __forceinline__ void tile_pass(
    const unsigned short* __restrict__ ks, const unsigned short* __restrict__ vt,
    unsigned short* __restrict__ Pw, bf16x8 qf0, bf16x8 qf1,
    int key0, int qrow, int klen, int quad, int l16,
    float& mst, float& lsum, f32x4 o[4]) {
  const f32x4 fz = {0.f, 0.f, 0.f, 0.f};
  f32x4 s[8];
#pragma unroll
  for (int nf = 0; nf < 8; nf++) {
    const int row = nf * 16 + l16;
    const int sw = row & 7;
    const bf16x8 kf0 = *(const bf16x8*)(ks + row * 64 + (quad ^ sw) * 8);
    const bf16x8 kf1 = *(const bf16x8*)(ks + row * 64 + ((quad + 4) ^ sw) * 8);
    f32x4 a = fz;
    a = __builtin_amdgcn_mfma_f32_16x16x32_bf16(kf0, qf0, a, 0, 0, 0);
    a = __builtin_amdgcn_mfma_f32_16x16x32_bf16(kf1, qf1, a, 0, 0, 0);
    s[nf] = a;
  }
  softmax_update<MASKED>(s, key0, qrow, klen, quad, l16, mst, lsum, o, Pw);
  bf16x8 pf[4];
#pragma unroll
  for (int ksn = 0; ksn < 4; ksn++)
    pf[ksn] = *(const bf16x8*)(Pw + l16 * 128 + ((ksn * 4 + quad) ^ l16) * 8);
#pragma unroll
  for (int db = 0; db < 4; db++) {
    const int d = db * 16 + l16;
#pragma unroll
    for (int ksn = 0; ksn < 4; ksn++) {
      const bf16x8 v = *(const bf16x8*)(vt + d * 128 + ((ksn * 4 + quad) ^ l16) * 8);
      o[db] = __builtin_amdgcn_mfma_f32_16x16x32_bf16(pf[ksn], v, o[db], 0, 0, 0);
    }
  }
}

__global__ __launch_bounds__(256, 3) void attn_kernel(
    const unsigned short* __restrict__ Qb, const unsigned short* __restrict__ Kb,
    const unsigned short* __restrict__ VTb, const float* __restrict__ qin,
    const int* __restrict__ lens, float* __restrict__ out) {
  const int pi = blockIdx.x, h = blockIdx.y, b = blockIdx.z;
  const int lo = pi, hi = 31 - pi;
  const int bh = b * NHEAD + h;
  const int t = threadIdx.x, wave = t >> 6, lane = t & 63, quad = lane >> 4, l16 = lane & 15;
  const int klen = lens[b], qlen = lens[2 + b];
  const bool doHI = (hi * 64 < qlen);

  __shared__ unsigned short Ks[128 * 64];     // [key][d], swizzle row&7
  __shared__ unsigned short VT[64 * 128];     // [d][key], swizzle d&15
  __shared__ unsigned short Ps[4][16 * 128];  // per-wave P, reused hi->lo

  const unsigned short* Qp = Qb + (size_t)bh * SEQ * HDIM;
  const unsigned short* Kp = Kb + (size_t)bh * SEQ * HDIM;
  const unsigned short* Vt = VTb + (size_t)bh * HDIM * SEQ;

  const int qrLO = lo * 64 + wave * 16 + l16;
  const int qrHI = hi * 64 + wave * 16 + l16;
  const bf16x8 qlo0 = *(const bf16x8*)(Qp + (size_t)qrLO * HDIM + quad * 8);
  const bf16x8 qlo1 = *(const bf16x8*)(Qp + (size_t)qrLO * HDIM + 32 + quad * 8);
  const bf16x8 qhi0 = *(const bf16x8*)(Qp + (size_t)qrHI * HDIM + quad * 8);
  const bf16x8 qhi1 = *(const bf16x8*)(Qp + (size_t)qrHI * HDIM + 32 + quad * 8);

  const f32x4 fz = {0.f, 0.f, 0.f, 0.f};
  f32x4 oLO[4], oHI[4];
#pragma unroll
  for (int i = 0; i < 4; i++) { oLO[i] = fz; oHI[i] = fz; }
  float mLO = -__builtin_inff(), lLO = 0.f;
  float mHI = -__builtin_inff(), lHI = 0.f;

  const int kendLO = ((lo * 64 + 64) < klen) ? (lo * 64 + 64) : klen;
  const int ktotLO = (kendLO + 127) >> 7;
  int ktotHI = 0;
  if (doHI) {
    const int kendHI = ((hi * 64 + 64) < klen) ? (hi * 64 + 64) : klen;
    ktotHI = (kendHI + 127) >> 7;
  }
  const int ktot = (ktotHI > ktotLO) ? ktotHI : ktotLO;

  for (int kt = 0; kt < ktot; kt++) {
    const int key0 = kt << 7;
    __syncthreads();  // all waves done with previous chunk's LDS
    // stage K: 128 rows x 64d (8 groups of 16B, swizzle row&7)
#pragma unroll
    for (int c = 0; c < 4; c++) {
      const int slot = c * 256 + t;
      const int row = slot >> 3, pg = slot & 7;
      async_copy16(Kp + (size_t)(key0 + row) * HDIM + (pg ^ (row & 7)) * 8,
                   (char*)Ks + (c * 256 + (t & 192)) * 16);
    }
    // stage V^T: 64 rows x 128 keys (16 groups of 16B, swizzle row&15)
#pragma unroll
    for (int c = 0; c < 4; c++) {
      const int slot = c * 256 + t;
      const int row = slot >> 4, pg = slot & 15;
      async_copy16(Vt + (size_t)row * SEQ + key0 + (pg ^ (row & 15)) * 8,
                   (char*)VT + (c * 256 + (t & 192)) * 16);
    }
    __syncthreads();  // async copies drained

    if (kt < ktotHI) {  // HI tile first (it has the most chunks)
      if ((key0 + 127 <= hi * 64) && (key0 + 127 < klen))
        tile_pass<false>(Ks, VT, Ps[wave], qhi0, qhi1, key0, qrHI, klen, quad, l16, mHI, lHI, oHI);
      else
        tile_pass<true>(Ks, VT, Ps[wave], qhi0, qhi1, key0, qrHI, klen, quad, l16, mHI, lHI, oHI);
    }
    if (kt < ktotLO) {
      if ((key0 + 127 <= lo * 64) && (key0 + 127 < klen))
        tile_pass<false>(Ks, VT, Ps[wave], qlo0, qlo1, key0, qrLO, klen, quad, l16, mLO, lLO, oLO);
      else
        tile_pass<true>(Ks, VT, Ps[wave], qlo0, qlo1, key0, qrLO, klen, quad, l16, mLO, lLO, oLO);
    }
  }

  const float invLO = (lLO > 0.f) ? 1.f / lLO : 0.f;
  const float invHI = (lHI > 0.f) ? 1.f / lHI : 0.f;
  float ibLO[4], ibHI[4];
#pragma unroll
  for (int r = 0; r < 4; r++) {
    ibLO[r] = __shfl(invLO, quad * 4 + r, 64);
    ibHI[r] = __shfl(invHI, quad * 4 + r, 64);
  }
#pragma unroll
  for (int db = 0; db < 4; db++) {
    const int col = h * HDIM + db * 16 + l16;
#pragma unroll
    for (int r = 0; r < 4; r++) {
      const int iL = lo * 64 + wave * 16 + quad * 4 + r;
      const int iH = hi * 64 + wave * 16 + quad * 4 + r;
      const size_t oL = (size_t)(b * SEQ + iL) * DMODEL + col;
      const size_t oH = (size_t)(b * SEQ + iH) * DMODEL + col;
      out[oL] = ((iL < qlen) ? oLO[db][r] * ibLO[r] : 0.f) + qin[oL];
      out[oH] = ((iH < qlen) ? oHI[db][r] * ibHI[r] : 0.f) + qin[oH];
    }
  }
}

extern "C" void kernel_launch(void* const* d_in, const int* in_sizes, int n_in,
                              void* d_out, int out_size, void* d_ws, size_t ws_size,
                              hipStream_t stream) {
  (void)in_sizes; (void)n_in; (void)out_size; (void)ws_size;
  const float* q = (const float*)d_in[0];
  const float* k = (const float*)d_in[1];
  const float* v = (const float*)d_in[2];
  const float* Wq = (const float*)d_in[3];
  const float* bq = (const float*)d_in[4];
  const float* Wk = (const float*)d_in[5];
  const float* bk = (const float*)d_in[6];
  const float* Wv = (const float*)d_in[7];
  const float* bv = (const float*)d_in[8];
  const unsigned char* kpm = (const unsigned char*)d_in[9];
  const unsigned char* qpm = (const unsigned char*)d_in[10];
  float* out = (float*)d_out;

  const size_t tsz = (size_t)BATCH * SEQ * DMODEL;  // 4 Mi
  const size_t wsz = (size_t)DMODEL * DMODEL;       // 1 Mi

  char* ws = (char*)d_ws;
  int* lens = (int*)ws;
  unsigned short* cvt_base = (unsigned short*)(ws + 256);
  unsigned short* qb16 = cvt_base;
  unsigned short* kb16 = qb16 + tsz;
  unsigned short* vb16 = kb16 + tsz;
  unsigned short* Wqb = vb16 + tsz;
  unsigned short* Wkb = Wqb + wsz;
  unsigned short* Wvb = Wkb + wsz;
  unsigned short* Qw = Wvb + wsz;
  unsigned short* Kw = Qw + tsz;
  unsigned short* Vtw = Kw + tsz;  // V^T [b,h,d,s]

  cvt_all<<<dim3(CVT_BLOCKS + 1), dim3(256), 0, stream>>>(q, k, v, Wq, Wk, Wv,
                                                          cvt_base, kpm, qpm, lens);
  qkv_proj<<<dim3(8, 32, 3), dim3(256), 0, stream>>>(qb16, kb16, vb16, Wqb, bq, Wkb, bk, Wvb, bv, Qw, Kw, Vtw);
  attn_kernel<<<dim3(16, NHEAD, BATCH), dim3(256), 0, stream>>>(Qw, Kw, Vtw, q, lens, out);
}

// Round 8
// 210.161 us; speedup vs baseline: 1.4161x; 1.0450x over previous
//
#include <hip/hip_runtime.h>
#include <stdint.h>

#define BATCH 2
#define SEQ 2048
#define DMODEL 1024
#define NHEAD 16
#define HDIM 64
#define CVT_BLOCKS 15360

typedef __attribute__((ext_vector_type(8))) short bf16x8;
typedef __attribute__((ext_vector_type(4))) float f32x4;

__device__ __forceinline__ unsigned short f2bf(float f) {
  unsigned int u = __float_as_uint(f);
  u += 0x7fffu + ((u >> 16) & 1u);
  return (unsigned short)(u >> 16);
}
// pack 2 f32 -> 2 bf16 (round-to-nearest-ties-away): 2 adds + 1 v_perm
__device__ __forceinline__ unsigned int pk2bf(float a, float b) {
  return __builtin_amdgcn_perm(__float_as_uint(b) + 0x8000u,
                               __float_as_uint(a) + 0x8000u, 0x07060302u);
}
__device__ __forceinline__ void async_copy16(const void* g, void* l) {
  __builtin_amdgcn_global_load_lds(
      (const __attribute__((address_space(1))) void*)g,
      (__attribute__((address_space(3))) void*)l, 16, 0, 0);
}

// ---- fp32 -> bf16 for q,k,v,Wq,Wk,Wv; block CVT_BLOCKS computes mask lens ----
__global__ __launch_bounds__(256) void cvt_all(
    const float* __restrict__ q, const float* __restrict__ k,
    const float* __restrict__ v, const float* __restrict__ Wq,
    const float* __restrict__ Wk, const float* __restrict__ Wv,
    unsigned short* __restrict__ dst,
    const unsigned char* __restrict__ kp, const unsigned char* __restrict__ qp,
    int* __restrict__ lens) {
  if (blockIdx.x == CVT_BLOCKS) {  // klen->lens[0..1], qlen->lens[2..3]
    const int t = threadIdx.x, wave = t >> 6, lane = t & 63;
    const unsigned char* base = (wave < 2) ? kp : qp;
    const int b = wave & 1;
    const bool bytefmt = (base[1] != 0);  // element 1 always valid (len>=S/2)
    int cnt = 0;
    if (bytefmt) {
      const uint4* p = (const uint4*)(base + (size_t)b * SEQ);
#pragma unroll
      for (int g = 0; g < 2; g++) {
        const uint4 x = p[g * 64 + lane];
        const unsigned int w[4] = {x.x, x.y, x.z, x.w};
#pragma unroll
        for (int i = 0; i < 4; i++) {
          const unsigned int ww = w[i];
          cnt += ((ww & 0xffu) != 0) + ((ww & 0xff00u) != 0) +
                 ((ww & 0xff0000u) != 0) + ((ww & 0xff000000u) != 0);
        }
      }
    } else {
      const uint4* p = (const uint4*)(base + (size_t)b * SEQ * 4);
#pragma unroll
      for (int g = 0; g < 8; g++) {
        const uint4 x = p[g * 64 + lane];
        cnt += (x.x != 0) + (x.y != 0) + (x.z != 0) + (x.w != 0);
      }
    }
#pragma unroll
    for (int off = 32; off >= 1; off >>= 1) cnt += __shfl_xor(cnt, off, 64);
    if (lane == 0) lens[wave] = cnt;
    return;
  }
  const int g = blockIdx.x * 256 + threadIdx.x;
  const float* src;
  size_t off, dbase;
  if (g < 3 * (1 << 20)) {
    const int ti = g >> 20;
    src = (ti == 0) ? q : (ti == 1) ? k : v;
    off = (size_t)(g & ((1 << 20) - 1));
    dbase = (size_t)ti << 22;
  } else {
    const int gw = g - 3 * (1 << 20);
    const int ti = gw >> 18;
    src = (ti == 0) ? Wq : (ti == 1) ? Wk : Wv;
    off = (size_t)(gw & ((1 << 18) - 1));
    dbase = (3ull << 22) + ((size_t)ti << 20);
  }
  const float4 x = ((const float4*)src)[off];
  ushort4 o;
  o.x = f2bf(x.x); o.y = f2bf(x.y); o.z = f2bf(x.z); o.w = f2bf(x.w);
  *(ushort4*)(dst + dbase + off * 4) = o;
}

// ---- fused QKV projection v2: BK=64, swizzled LDS, packed 8B stores, skip.
// Q pre-scaled by (1/sqrt(64))*log2(e). Q/K: swapped mfma -> acc rows = out-dim
// (4 in-lane elems = consecutive hd). V: normal mfma -> acc rows = seq
// (4 in-lane elems = consecutive s) -> writes V^T[b,h,d,s].
__global__ __launch_bounds__(256) void qkv_proj(
    const unsigned short* __restrict__ xq, const unsigned short* __restrict__ xk,
    const unsigned short* __restrict__ xv,
    const unsigned short* __restrict__ Wq, const float* __restrict__ bq,
    const unsigned short* __restrict__ Wk, const float* __restrict__ bk,
    const unsigned short* __restrict__ Wv, const float* __restrict__ bv,
    unsigned short* __restrict__ Qo, unsigned short* __restrict__ Ko,
    unsigned short* __restrict__ Vo, const int* __restrict__ lens) {
  const int z = blockIdx.z;
  const int m0 = blockIdx.y * 128, n0 = blockIdx.x * 128;
  const int b = m0 >> 11;
  const int len = (z == 0) ? lens[2 + b] : lens[b];
  if ((m0 & (SEQ - 1)) >= len) return;  // rows never read downstream (poison benign)

  const unsigned short* x = (z == 0) ? xq : (z == 1) ? xk : xv;
  const unsigned short* W = (z == 0) ? Wq : (z == 1) ? Wk : Wv;
  const float* bias = (z == 0) ? bq : (z == 1) ? bk : bv;
  unsigned short* dst = (z == 0) ? Qo : (z == 1) ? Ko : Vo;
  const float osc = (z == 0) ? 0.18033688011112042f : 1.0f;

  __shared__ unsigned short As[128 * 64];  // row=64 shorts, 8x16B groups, swizzle row&7
  __shared__ unsigned short Bs[128 * 64];

  const int t = threadIdx.x;
  const int wave = t >> 6, lane = t & 63, quad = lane >> 4, l16 = lane & 15;
  const int wm = wave >> 1, wn = wave & 1;

  const f32x4 fz = {0.f, 0.f, 0.f, 0.f};
  f32x4 acc[4][4];
#pragma unroll
  for (int i = 0; i < 4; i++)
#pragma unroll
    for (int j = 0; j < 4; j++) acc[i][j] = fz;

  for (int k0 = 0; k0 < DMODEL; k0 += 64) {
    __syncthreads();
#pragma unroll
    for (int c = 0; c < 4; c++) {
      const int slot = c * 256 + t;
      const int row = slot >> 3, pg = slot & 7;
      const int lg = (pg ^ (row & 7)) * 8;
      async_copy16(x + (size_t)(m0 + row) * DMODEL + k0 + lg,
                   (char*)As + (c * 256 + (t & 192)) * 16);
      async_copy16(W + (size_t)(n0 + row) * DMODEL + k0 + lg,
                   (char*)Bs + (c * 256 + (t & 192)) * 16);
    }
    __syncthreads();
#pragma unroll
    for (int kk = 0; kk < 2; kk++) {
      bf16x8 af[4], bfr[4];
#pragma unroll
      for (int i = 0; i < 4; i++) {
        const int ra = wm * 64 + i * 16 + l16;
        const int rb = wn * 64 + i * 16 + l16;
        af[i] = *(const bf16x8*)(As + ra * 64 + ((kk * 4 + quad) ^ (ra & 7)) * 8);
        bfr[i] = *(const bf16x8*)(Bs + rb * 64 + ((kk * 4 + quad) ^ (rb & 7)) * 8);
      }
      if (z == 2) {
#pragma unroll
        for (int i = 0; i < 4; i++)
#pragma unroll
          for (int j = 0; j < 4; j++)
            acc[i][j] = __builtin_amdgcn_mfma_f32_16x16x32_bf16(af[i], bfr[j], acc[i][j], 0, 0, 0);
      } else {
#pragma unroll
        for (int i = 0; i < 4; i++)
#pragma unroll
          for (int j = 0; j < 4; j++)
            acc[i][j] = __builtin_amdgcn_mfma_f32_16x16x32_bf16(bfr[j], af[i], acc[i][j], 0, 0, 0);
      }
    }
  }

  if (z == 2) {
    // acc rows (quad*4+r) = s, cols (l16) = n -> V^T[b,h,hd,s]: 4 consecutive s
#pragma unroll
    for (int j = 0; j < 4; j++) {
      const int n = n0 + wn * 64 + j * 16 + l16;
      const float bb_ = bias[n];
      const int h = n >> 6, hd = n & 63;
#pragma unroll
      for (int i = 0; i < 4; i++) {
        const int s0 = (m0 & (SEQ - 1)) + wm * 64 + i * 16 + quad * 4;
        uint2 w;
        w.x = pk2bf(acc[i][j][0] + bb_, acc[i][j][1] + bb_);
        w.y = pk2bf(acc[i][j][2] + bb_, acc[i][j][3] + bb_);
        *(uint2*)(dst + (((size_t)(b * NHEAD + h) * HDIM + hd) << 11) + s0) = w;
      }
    }
  } else {
    // acc rows (quad*4+r) = n, cols (l16) = s -> [b,h,s,hd]: 4 consecutive hd
#pragma unroll
    for (int j = 0; j < 4; j++) {
      const int nb = n0 + wn * 64 + j * 16 + quad * 4;
      const float4 b4 = *(const float4*)(bias + nb);
      const int h = nb >> 6, hd0 = nb & 63;
#pragma unroll
      for (int i = 0; i < 4; i++) {
        const int s = (m0 & (SEQ - 1)) + wm * 64 + i * 16 + l16;
        uint2 w;
        w.x = pk2bf((acc[i][j][0] + b4.x) * osc, (acc[i][j][1] + b4.y) * osc);
        w.y = pk2bf((acc[i][j][2] + b4.z) * osc, (acc[i][j][3] + b4.w) * osc);
        *(uint2*)(dst + (((size_t)(b * NHEAD + h) * SEQ + s) << 6) + hd0) = w;
      }
    }
  }
}

// ===== attention v6 (unchanged from R7): paired causal tiles, sequential =====

template <bool MASKED>
__device__ __forceinline__ void softmax_update(
    const f32x4 s[8], int key0, int qrow, int klen, int quad, int l16,
    float& mst, float& lsum, f32x4 o[4], unsigned short* Pdst) {
  float pm[8][4];
  float rm = -__builtin_inff();
  if (MASKED) {
    const int kmax = ((qrow < klen - 1) ? qrow : klen - 1) - key0 - quad * 4;
#pragma unroll
    for (int nf = 0; nf < 8; nf++)
#pragma unroll
      for (int r = 0; r < 4; r++) {
        pm[nf][r] = (nf * 16 + r <= kmax) ? s[nf][r] : -__builtin_inff();
        rm = fmaxf(rm, pm[nf][r]);
      }
  } else {
#pragma unroll
    for (int nf = 0; nf < 8; nf++)
#pragma unroll
      for (int r = 0; r < 4; r++) {
        pm[nf][r] = s[nf][r];
        rm = fmaxf(rm, pm[nf][r]);
      }
  }
  rm = fmaxf(rm, __shfl_xor(rm, 16, 64));
  rm = fmaxf(rm, __shfl_xor(rm, 32, 64));
  if (__ballot(rm > mst) != 0ull) {
    const float mnew = fmaxf(mst, rm);
    const float alpha = exp2f(fmaxf(mst, -1e30f) - fmaxf(mnew, -1e30f));
    mst = mnew;
    lsum *= alpha;
    float ab[4];
#pragma unroll
    for (int r = 0; r < 4; r++) ab[r] = __shfl(alpha, quad * 4 + r, 64);
#pragma unroll
    for (int db = 0; db < 4; db++)
#pragma unroll
      for (int r = 0; r < 4; r++) o[db][r] *= ab[r];
  }
  const float mref = fmaxf(mst, -1e30f);
  float rs = 0.f;
#pragma unroll
  for (int nf = 0; nf < 8; nf++)
#pragma unroll
    for (int r = 0; r < 4; r++) {
      const float p = exp2f(pm[nf][r] - mref);
      pm[nf][r] = p;
      rs += p;
    }
  rs += __shfl_xor(rs, 16, 64);
  rs += __shfl_xor(rs, 32, 64);
  lsum += rs;
#pragma unroll
  for (int nf = 0; nf < 8; nf++) {
    uint2 w;
    w.x = pk2bf(pm[nf][0], pm[nf][1]);
    w.y = pk2bf(pm[nf][2], pm[nf][3]);
    const int grp = (nf * 2 + (quad >> 1)) ^ l16;
    *(uint2*)(Pdst + l16 * 128 + grp * 8 + (quad & 1) * 4) = w;
  }
}

template <bool MASKED>
__device__ __forceinline__ void tile_pass(
    const unsigned short* __restrict__ ks, const unsigned short* __restrict__ vt,
    unsigned short* __restrict__ Pw, bf16x8 qf0, bf16x8 qf1,
    int key0, int qrow, int klen, int quad, int l16,
    float& mst, float& lsum, f32x4 o[4]) {
  const f32x4 fz = {0.f, 0.f, 0.f, 0.f};
  f32x4 s[8];
#pragma unroll
  for (int nf = 0; nf < 8; nf++) {
    const int row = nf * 16 + l16;
    const int sw = row & 7;
    const bf16x8 kf0 = *(const bf16x8*)(ks + row * 64 + (quad ^ sw) * 8);
    const bf16x8 kf1 = *(const bf16x8*)(ks + row * 64 + ((quad + 4) ^ sw) * 8);
    f32x4 a = fz;
    a = __builtin_amdgcn_mfma_f32_16x16x32_bf16(kf0, qf0, a, 0, 0, 0);
    a = __builtin_amdgcn_mfma_f32_16x16x32_bf16(kf1, qf1, a, 0, 0, 0);
    s[nf] = a;
  }
  softmax_update<MASKED>(s, key0, qrow, klen, quad, l16, mst, lsum, o, Pw);
  bf16x8 pf[4];
#pragma unroll
  for (int ksn = 0; ksn < 4; ksn++)
    pf[ksn] = *(const bf16x8*)(Pw + l16 * 128 + ((ksn * 4 + quad) ^ l16) * 8);
#pragma unroll
  for (int db = 0; db < 4; db++) {
    const int d = db * 16 + l16;
#pragma unroll
    for (int ksn = 0; ksn < 4; ksn++) {
      const bf16x8 v = *(const bf16x8*)(vt + d * 128 + ((ksn * 4 + quad) ^ l16) * 8);
      o[db] = __builtin_amdgcn_mfma_f32_16x16x32_bf16(pf[ksn], v, o[db], 0, 0, 0);
    }
  }
}

__global__ __launch_bounds__(256, 3) void attn_kernel(
    const unsigned short* __restrict__ Qb, const unsigned short* __restrict__ Kb,
    const unsigned short* __restrict__ VTb, const float* __restrict__ qin,
    const int* __restrict__ lens, float* __restrict__ out) {
  const int pi = blockIdx.x, h = blockIdx.y, b = blockIdx.z;
  const int lo = pi, hi = 31 - pi;
  const int bh = b * NHEAD + h;
  const int t = threadIdx.x, wave = t >> 6, lane = t & 63, quad = lane >> 4, l16 = lane & 15;
  const int klen = lens[b], qlen = lens[2 + b];
  const bool doHI = (hi * 64 < qlen);

  __shared__ unsigned short Ks[128 * 64];     // [key][d], swizzle row&7
  __shared__ unsigned short VT[64 * 128];     // [d][key], swizzle d&15
  __shared__ unsigned short Ps[4][16 * 128];  // per-wave P, reused hi->lo

  const unsigned short* Qp = Qb + (size_t)bh * SEQ * HDIM;
  const unsigned short* Kp = Kb + (size_t)bh * SEQ * HDIM;
  const unsigned short* Vt = VTb + (size_t)bh * HDIM * SEQ;

  const int qrLO = lo * 64 + wave * 16 + l16;
  const int qrHI = hi * 64 + wave * 16 + l16;
  const bf16x8 qlo0 = *(const bf16x8*)(Qp + (size_t)qrLO * HDIM + quad * 8);
  const bf16x8 qlo1 = *(const bf16x8*)(Qp + (size_t)qrLO * HDIM + 32 + quad * 8);
  const bf16x8 qhi0 = *(const bf16x8*)(Qp + (size_t)qrHI * HDIM + quad * 8);
  const bf16x8 qhi1 = *(const bf16x8*)(Qp + (size_t)qrHI * HDIM + 32 + quad * 8);

  const f32x4 fz = {0.f, 0.f, 0.f, 0.f};
  f32x4 oLO[4], oHI[4];
#pragma unroll
  for (int i = 0; i < 4; i++) { oLO[i] = fz; oHI[i] = fz; }
  float mLO = -__builtin_inff(), lLO = 0.f;
  float mHI = -__builtin_inff(), lHI = 0.f;

  const int kendLO = ((lo * 64 + 64) < klen) ? (lo * 64 + 64) : klen;
  const int ktotLO = (kendLO + 127) >> 7;
  int ktotHI = 0;
  if (doHI) {
    const int kendHI = ((hi * 64 + 64) < klen) ? (hi * 64 + 64) : klen;
    ktotHI = (kendHI + 127) >> 7;
  }
  const int ktot = (ktotHI > ktotLO) ? ktotHI : ktotLO;

  for (int kt = 0; kt < ktot; kt++) {
    const int key0 = kt << 7;
    __syncthreads();
#pragma unroll
    for (int c = 0; c < 4; c++) {
      const int slot = c * 256 + t;
      const int row = slot >> 3, pg = slot & 7;
      async_copy16(Kp + (size_t)(key0 + row) * HDIM + (pg ^ (row & 7)) * 8,
                   (char*)Ks + (c * 256 + (t & 192)) * 16);
    }
#pragma unroll
    for (int c = 0; c < 4; c++) {
      const int slot = c * 256 + t;
      const int row = slot >> 4, pg = slot & 15;
      async_copy16(Vt + (size_t)row * SEQ + key0 + (pg ^ (row & 15)) * 8,
                   (char*)VT + (c * 256 + (t & 192)) * 16);
    }
    __syncthreads();

    if (kt < ktotHI) {
      if ((key0 + 127 <= hi * 64) && (key0 + 127 < klen))
        tile_pass<false>(Ks, VT, Ps[wave], qhi0, qhi1, key0, qrHI, klen, quad, l16, mHI, lHI, oHI);
      else
        tile_pass<true>(Ks, VT, Ps[wave], qhi0, qhi1, key0, qrHI, klen, quad, l16, mHI, lHI, oHI);
    }
    if (kt < ktotLO) {
      if ((key0 + 127 <= lo * 64) && (key0 + 127 < klen))
        tile_pass<false>(Ks, VT, Ps[wave], qlo0, qlo1, key0, qrLO, klen, quad, l16, mLO, lLO, oLO);
      else
        tile_pass<true>(Ks, VT, Ps[wave], qlo0, qlo1, key0, qrLO, klen, quad, l16, mLO, lLO, oLO);
    }
  }

  const float invLO = (lLO > 0.f) ? 1.f / lLO : 0.f;
  const float invHI = (lHI > 0.f) ? 1.f / lHI : 0.f;
  float ibLO[4], ibHI[4];
#pragma unroll
  for (int r = 0; r < 4; r++) {
    ibLO[r] = __shfl(invLO, quad * 4 + r, 64);
    ibHI[r] = __shfl(invHI, quad * 4 + r, 64);
  }
#pragma unroll
  for (int db = 0; db < 4; db++) {
    const int col = h * HDIM + db * 16 + l16;
#pragma unroll
    for (int r = 0; r < 4; r++) {
      const int iL = lo * 64 + wave * 16 + quad * 4 + r;
      const int iH = hi * 64 + wave * 16 + quad * 4 + r;
      const size_t oL = (size_t)(b * SEQ + iL) * DMODEL + col;
      const size_t oH = (size_t)(b * SEQ + iH) * DMODEL + col;
      out[oL] = ((iL < qlen) ? oLO[db][r] * ibLO[r] : 0.f) + qin[oL];
      out[oH] = ((iH < qlen) ? oHI[db][r] * ibHI[r] : 0.f) + qin[oH];
    }
  }
}

extern "C" void kernel_launch(void* const* d_in, const int* in_sizes, int n_in,
                              void* d_out, int out_size, void* d_ws, size_t ws_size,
                              hipStream_t stream) {
  (void)in_sizes; (void)n_in; (void)out_size; (void)ws_size;
  const float* q = (const float*)d_in[0];
  const float* k = (const float*)d_in[1];
  const float* v = (const float*)d_in[2];
  const float* Wq = (const float*)d_in[3];
  const float* bq = (const float*)d_in[4];
  const float* Wk = (const float*)d_in[5];
  const float* bk = (const float*)d_in[6];
  const float* Wv = (const float*)d_in[7];
  const float* bv = (const float*)d_in[8];
  const unsigned char* kpm = (const unsigned char*)d_in[9];
  const unsigned char* qpm = (const unsigned char*)d_in[10];
  float* out = (float*)d_out;

  const size_t tsz = (size_t)BATCH * SEQ * DMODEL;  // 4 Mi
  const size_t wsz = (size_t)DMODEL * DMODEL;       // 1 Mi

  char* ws = (char*)d_ws;
  int* lens = (int*)ws;
  unsigned short* cvt_base = (unsigned short*)(ws + 256);
  unsigned short* qb16 = cvt_base;
  unsigned short* kb16 = qb16 + tsz;
  unsigned short* vb16 = kb16 + tsz;
  unsigned short* Wqb = vb16 + tsz;
  unsigned short* Wkb = Wqb + wsz;
  unsigned short* Wvb = Wkb + wsz;
  unsigned short* Qw = Wvb + wsz;
  unsigned short* Kw = Qw + tsz;
  unsigned short* Vtw = Kw + tsz;  // V^T [b,h,d,s]

  cvt_all<<<dim3(CVT_BLOCKS + 1), dim3(256), 0, stream>>>(q, k, v, Wq, Wk, Wv,
                                                          cvt_base, kpm, qpm, lens);
  qkv_proj<<<dim3(8, 32, 3), dim3(256), 0, stream>>>(qb16, kb16, vb16, Wqb, bq, Wkb, bk, Wvb, bv, Qw, Kw, Vtw, lens);
  attn_kernel<<<dim3(16, NHEAD, BATCH), dim3(256), 0, stream>>>(Qw, Kw, Vtw, q, lens, out);
}